// Round 3
// baseline (168.577 us; speedup 1.0000x reference)
//
#include <hip/hip_runtime.h>

typedef float f32x4 __attribute__((ext_vector_type(4)));
typedef __bf16 bf16x8 __attribute__((ext_vector_type(8)));

#define H_DIM 4096
#define I_DIM 11008
#define MK 64                    // macro-K (floats): 256B contiguous burst per row
#define MACROS1 (H_DIM / MK)     // 64
#define MACROS2 (I_DIM / MK)     // 172

// 2:4 prune of one contiguous group of 4 (matches jnp.argsort stable-tie
// semantics: keep element i iff #{j: |wj|<|wi| or (|wj|==|wi| and j<i)} >= 2)
__device__ __forceinline__ f32x4 prune4(f32x4 w) {
    float a0 = fabsf(w[0]), a1 = fabsf(w[1]), a2 = fabsf(w[2]), a3 = fabsf(w[3]);
    int r0 = (int)(a1 < a0) + (int)(a2 < a0) + (int)(a3 < a0);
    int r1 = (int)(a0 <= a1) + (int)(a2 < a1) + (int)(a3 < a1);
    int r2 = (int)(a0 <= a2) + (int)(a1 <= a2) + (int)(a3 < a2);
    int r3 = (int)(a0 <= a3) + (int)(a1 <= a3) + (int)(a2 <= a3);
    w[0] = (r0 >= 2) ? w[0] : 0.0f;
    w[1] = (r1 >= 2) ? w[1] : 0.0f;
    w[2] = (r2 >= 2) ? w[2] : 0.0f;
    w[3] = (r3 >= 2) ? w[3] : 0.0f;
    return w;
}

__device__ __forceinline__ bf16x8 cvt8(f32x4 a, f32x4 b) {
    bf16x8 r;
    r[0] = (__bf16)a[0]; r[1] = (__bf16)a[1];
    r[2] = (__bf16)a[2]; r[3] = (__bf16)a[3];
    r[4] = (__bf16)b[0]; r[5] = (__bf16)b[1];
    r[6] = (__bf16)b[2]; r[7] = (__bf16)b[3];
    return r;
}

// split s of nsplit over `total` macro-iters: first r splits get q+1
__device__ __forceinline__ void ksplit(int s, int nsplit, int total,
                                       int& mbeg, int& miters) {
    int q = total / nsplit, r = total % nsplit;
    miters = q + (s < r ? 1 : 0);
    mbeg = s * q + (s < r ? s : r);
}

__global__ __launch_bounds__(256) void k_cvt_x(const float* __restrict__ x,
                                               __bf16* __restrict__ xb) {
    int i = (blockIdx.x * 256 + threadIdx.x) * 4;
    f32x4 v = *(const f32x4*)(x + i);
    xb[i + 0] = (__bf16)v[0]; xb[i + 1] = (__bf16)v[1];
    xb[i + 2] = (__bf16)v[2]; xb[i + 3] = (__bf16)v[3];
}

// gate+up fused: wave = 16 output cols x 32 tokens; k-split via blockIdx.y.
// Macro-iter loads a contiguous 256B window of each of the wave's 16 rows
// (per array) in one batch of back-to-back dwordx4's -> DRAM page locality.
__global__ __launch_bounds__(256, 5) void k_gateup(
        const float* __restrict__ GW, const float* __restrict__ UW,
        const __bf16* __restrict__ XB,
        float* __restrict__ gpart, float* __restrict__ upart, int nsplit) {
    const int lane = threadIdx.x & 63;
    const int wv   = threadIdx.x >> 6;
    const int i0   = (blockIdx.x * 4 + wv) * 16;   // 172 blocks * 4 * 16 = 11008
    const int s    = blockIdx.y;
    int mbeg, miters;
    ksplit(s, nsplit, MACROS1, mbeg, miters);
    const int kbeg = mbeg * MK;
    const int lrow = lane & 15;
    const int lk   = (lane >> 4) << 3;

    const float*  gp  = GW + (size_t)(i0 + lrow) * H_DIM + kbeg + lk;
    const float*  up  = UW + (size_t)(i0 + lrow) * H_DIM + kbeg + lk;
    const __bf16* xp0 = XB + (size_t)lrow * H_DIM + kbeg + lk;
    const __bf16* xp1 = xp0 + (size_t)16 * H_DIM;

    f32x4 aG0 = {0,0,0,0}, aG1 = {0,0,0,0}, aU0 = {0,0,0,0}, aU1 = {0,0,0,0};

    #pragma unroll 1
    for (int m = 0; m < miters; ++m) {
        const int ko = m * MK;
        // ---- batch ALL loads (covers 256B contiguous per row per array) ----
        f32x4 g00 = *(const f32x4*)(gp + ko);
        f32x4 g01 = *(const f32x4*)(gp + ko + 4);
        f32x4 g10 = *(const f32x4*)(gp + ko + 32);
        f32x4 g11 = *(const f32x4*)(gp + ko + 36);
        f32x4 u00 = *(const f32x4*)(up + ko);
        f32x4 u01 = *(const f32x4*)(up + ko + 4);
        f32x4 u10 = *(const f32x4*)(up + ko + 32);
        f32x4 u11 = *(const f32x4*)(up + ko + 36);
        bf16x8 a00 = *(const bf16x8*)(xp0 + ko);
        bf16x8 a01 = *(const bf16x8*)(xp1 + ko);
        bf16x8 a10 = *(const bf16x8*)(xp0 + ko + 32);
        bf16x8 a11 = *(const bf16x8*)(xp1 + ko + 32);
        // ---- sub-iter 0: k in [ko, ko+32) ----
        bf16x8 bg = cvt8(prune4(g00), prune4(g01));
        bf16x8 bu = cvt8(prune4(u00), prune4(u01));
        aG0 = __builtin_amdgcn_mfma_f32_16x16x32_bf16(a00, bg, aG0, 0, 0, 0);
        aG1 = __builtin_amdgcn_mfma_f32_16x16x32_bf16(a01, bg, aG1, 0, 0, 0);
        aU0 = __builtin_amdgcn_mfma_f32_16x16x32_bf16(a00, bu, aU0, 0, 0, 0);
        aU1 = __builtin_amdgcn_mfma_f32_16x16x32_bf16(a01, bu, aU1, 0, 0, 0);
        // ---- sub-iter 1: k in [ko+32, ko+64) ----
        bg = cvt8(prune4(g10), prune4(g11));
        bu = cvt8(prune4(u10), prune4(u11));
        aG0 = __builtin_amdgcn_mfma_f32_16x16x32_bf16(a10, bg, aG0, 0, 0, 0);
        aG1 = __builtin_amdgcn_mfma_f32_16x16x32_bf16(a11, bg, aG1, 0, 0, 0);
        aU0 = __builtin_amdgcn_mfma_f32_16x16x32_bf16(a10, bu, aU0, 0, 0, 0);
        aU1 = __builtin_amdgcn_mfma_f32_16x16x32_bf16(a11, bu, aU1, 0, 0, 0);
    }

    const int col = i0 + lrow;
    const int t0  = (lane >> 4) * 4;          // C/D: col=lane&15, row=(lane>>4)*4+r
    const size_t srow = (size_t)s * 32;
    #pragma unroll
    for (int r = 0; r < 4; ++r) {
        size_t iA = (srow + t0 + r) * I_DIM + col;
        size_t iB = (srow + t0 + 16 + r) * I_DIM + col;
        gpart[iA] = aG0[r];  gpart[iB] = aG1[r];
        upart[iA] = aU0[r];  upart[iB] = aU1[r];
    }
}

__global__ __launch_bounds__(256) void k_hidden(
        const float* __restrict__ gpart, const float* __restrict__ upart,
        const float* __restrict__ gb, const float* __restrict__ ub,
        __bf16* __restrict__ hb, int nsplit) {
    const int i = blockIdx.x * 256 + threadIdx.x;  // 43*256 = 11008
    const int t = blockIdx.y;
    float g = gb[i], u = ub[i];
    for (int s = 0; s < nsplit; ++s) {
        g += gpart[(size_t)(s * 32 + t) * I_DIM + i];
        u += upart[(size_t)(s * 32 + t) * I_DIM + i];
    }
    float h = g / (1.0f + __expf(-g)) * u;   // silu(g)*u
    hb[(size_t)t * I_DIM + i] = (__bf16)h;
}

__global__ __launch_bounds__(256, 6) void k_down(
        const float* __restrict__ DW, const __bf16* __restrict__ HB,
        float* __restrict__ opart, int nsplit) {
    const int lane = threadIdx.x & 63;
    const int wv   = threadIdx.x >> 6;
    const int o0   = (blockIdx.x * 4 + wv) * 16;   // 64 blocks * 4 * 16 = 4096
    const int s    = blockIdx.y;
    int mbeg, miters;
    ksplit(s, nsplit, MACROS2, mbeg, miters);
    const int kbeg = mbeg * MK;
    const int lrow = lane & 15;
    const int lk   = (lane >> 4) << 3;

    const float*  dp  = DW + (size_t)(o0 + lrow) * I_DIM + kbeg + lk;
    const __bf16* hp0 = HB + (size_t)lrow * I_DIM + kbeg + lk;
    const __bf16* hp1 = hp0 + (size_t)16 * I_DIM;

    f32x4 acc0 = {0,0,0,0}, acc1 = {0,0,0,0};

    #pragma unroll 1
    for (int m = 0; m < miters; ++m) {
        const int ko = m * MK;
        f32x4 d00 = *(const f32x4*)(dp + ko);
        f32x4 d01 = *(const f32x4*)(dp + ko + 4);
        f32x4 d10 = *(const f32x4*)(dp + ko + 32);
        f32x4 d11 = *(const f32x4*)(dp + ko + 36);
        bf16x8 h00 = *(const bf16x8*)(hp0 + ko);
        bf16x8 h01 = *(const bf16x8*)(hp1 + ko);
        bf16x8 h10 = *(const bf16x8*)(hp0 + ko + 32);
        bf16x8 h11 = *(const bf16x8*)(hp1 + ko + 32);

        bf16x8 bw = cvt8(d00, d01);
        acc0 = __builtin_amdgcn_mfma_f32_16x16x32_bf16(h00, bw, acc0, 0, 0, 0);
        acc1 = __builtin_amdgcn_mfma_f32_16x16x32_bf16(h01, bw, acc1, 0, 0, 0);
        bw = cvt8(d10, d11);
        acc0 = __builtin_amdgcn_mfma_f32_16x16x32_bf16(h10, bw, acc0, 0, 0, 0);
        acc1 = __builtin_amdgcn_mfma_f32_16x16x32_bf16(h11, bw, acc1, 0, 0, 0);
    }

    const int col = o0 + lrow;
    const int t0  = (lane >> 4) * 4;
    const size_t srow = (size_t)s * 32;
    #pragma unroll
    for (int r = 0; r < 4; ++r) {
        opart[(srow + t0 + r) * H_DIM + col]      = acc0[r];
        opart[(srow + t0 + 16 + r) * H_DIM + col] = acc1[r];
    }
}

__global__ __launch_bounds__(256) void k_out(
        const float* __restrict__ opart, const float* __restrict__ db,
        float* __restrict__ out, int nsplit) {
    const int o = blockIdx.x * 256 + threadIdx.x;  // 16*256 = 4096
    const int t = blockIdx.y;
    float v = db[o];
    for (int s = 0; s < nsplit; ++s)
        v += opart[(size_t)(s * 32 + t) * H_DIM + o];
    out[(size_t)t * H_DIM + o] = v;
}

extern "C" void kernel_launch(void* const* d_in, const int* in_sizes, int n_in,
                              void* d_out, int out_size, void* d_ws, size_t ws_size,
                              hipStream_t stream) {
    const float* x  = (const float*)d_in[0];
    const float* gw = (const float*)d_in[1];
    const float* uw = (const float*)d_in[2];
    const float* dw = (const float*)d_in[3];
    const float* gb = (const float*)d_in[4];
    const float* ub = (const float*)d_in[5];
    const float* db = (const float*)d_in[6];
    float* out = (float*)d_out;

    const size_t XB_BYTES = (size_t)32 * H_DIM * 2;          // 256 KiB
    const size_t HB_BYTES = (size_t)32 * I_DIM * 2;          // 688 KiB
    const size_t GP_UNIT  = (size_t)32 * I_DIM * 4;          // 1.38 MiB per split
    const size_t OP_UNIT  = (size_t)32 * H_DIM * 4;          // 0.5 MiB per split

    // deterministic split choice: shrink if ws is tight
    int ns1 = 8, ns2 = 16;
    while (ns1 > 4 &&
           XB_BYTES + HB_BYTES + 2 * GP_UNIT * ns1 + OP_UNIT * ns2 > ws_size)
        ns1 >>= 1;
    while (ns2 > 8 &&
           XB_BYTES + HB_BYTES + 2 * GP_UNIT * ns1 + OP_UNIT * ns2 > ws_size)
        ns2 >>= 1;

    char* ws = (char*)d_ws;
    __bf16* xb    = (__bf16*)(ws);
    __bf16* hb    = (__bf16*)(ws + XB_BYTES);
    float*  gpart = (float*)(ws + XB_BYTES + HB_BYTES);
    float*  upart = (float*)(ws + XB_BYTES + HB_BYTES + GP_UNIT * ns1);
    float*  opart = (float*)(ws + XB_BYTES + HB_BYTES + 2 * GP_UNIT * ns1);

    k_cvt_x <<<dim3(128),       dim3(256), 0, stream>>>(x, xb);
    k_gateup<<<dim3(172, ns1),  dim3(256), 0, stream>>>(gw, uw, xb, gpart, upart, ns1);
    k_hidden<<<dim3(43, 32),    dim3(256), 0, stream>>>(gpart, upart, gb, ub, hb, ns1);
    k_down  <<<dim3(64, ns2),   dim3(256), 0, stream>>>(dw, hb, opart, ns2);
    k_out   <<<dim3(16, 32),    dim3(256), 0, stream>>>(opart, db, out, ns2);
}

// Round 4
// 165.773 us; speedup vs baseline: 1.0169x; 1.0169x over previous
//
#include <hip/hip_runtime.h>

typedef float f32x4 __attribute__((ext_vector_type(4)));
typedef __bf16 bf16x8 __attribute__((ext_vector_type(8)));

#define H_DIM 4096
#define I_DIM 11008
#define BK 256                    // k floats per step = 1 KB per row chunk
#define KSTEPS_GU (H_DIM / BK)    // 16
#define KSTEPS_DN (I_DIM / BK)    // 43

// 2:4 prune of one contiguous group of 4 (stable argsort tie semantics)
__device__ __forceinline__ f32x4 prune4(f32x4 w) {
    float a0 = fabsf(w[0]), a1 = fabsf(w[1]), a2 = fabsf(w[2]), a3 = fabsf(w[3]);
    int r0 = (int)(a1 < a0) + (int)(a2 < a0) + (int)(a3 < a0);
    int r1 = (int)(a0 <= a1) + (int)(a2 < a1) + (int)(a3 < a1);
    int r2 = (int)(a0 <= a2) + (int)(a1 <= a2) + (int)(a3 < a2);
    int r3 = (int)(a0 <= a3) + (int)(a1 <= a3) + (int)(a2 <= a3);
    w[0] = (r0 >= 2) ? w[0] : 0.0f;
    w[1] = (r1 >= 2) ? w[1] : 0.0f;
    w[2] = (r2 >= 2) ? w[2] : 0.0f;
    w[3] = (r3 >= 2) ? w[3] : 0.0f;
    return w;
}

__device__ __forceinline__ bf16x8 cvt8(f32x4 a, f32x4 b) {
    bf16x8 r;
    r[0] = (__bf16)a[0]; r[1] = (__bf16)a[1];
    r[2] = (__bf16)a[2]; r[3] = (__bf16)a[3];
    r[4] = (__bf16)b[0]; r[5] = (__bf16)b[1];
    r[6] = (__bf16)b[2]; r[7] = (__bf16)b[3];
    return r;
}

__device__ __forceinline__ void gll16(const void* g, void* l) {
    __builtin_amdgcn_global_load_lds(
        (const __attribute__((address_space(1))) void*)g,
        (__attribute__((address_space(3))) void*)l, 16, 0, 0);
}

// split s of nsplit over `total` k-steps
__device__ __forceinline__ void ksplit(int s, int nsplit, int total,
                                       int& beg, int& cnt) {
    int q = total / nsplit, r = total % nsplit;
    cnt = q + (s < r ? 1 : 0);
    beg = s * q + (s < r ? s : r);
}

__global__ __launch_bounds__(256) void k_cvt_x(const float* __restrict__ x,
                                               __bf16* __restrict__ xb) {
    int i = (blockIdx.x * 256 + threadIdx.x) * 4;
    f32x4 v = *(const f32x4*)(x + i);
    xb[i + 0] = (__bf16)v[0]; xb[i + 1] = (__bf16)v[1];
    xb[i + 2] = (__bf16)v[2]; xb[i + 3] = (__bf16)v[3];
}

// gate+up fused, LDS-staged. Block: 32 W-rows x 32 tokens, 4 waves (2 rowgrp x
// 2 tokgrp). Staging: one global_load_lds per (array,row) = 1 KB contiguous,
// source XOR-preswizzled so strided ds_read_b128 is bank-conflict-free.
__global__ __launch_bounds__(256) void k_gateup(
        const float* __restrict__ GW, const float* __restrict__ UW,
        const __bf16* __restrict__ XB,
        float* __restrict__ gpart, float* __restrict__ upart, int nsplit) {
    __shared__ float ldsw[2][32][BK];      // [G/U][row][k]  64 KiB
    const int lane = threadIdx.x & 63;
    const int wv   = threadIdx.x >> 6;
    const int i0   = blockIdx.x * 32;      // 344 tiles
    int kbegstep, ksteps;
    ksplit(blockIdx.y, nsplit, KSTEPS_GU, kbegstep, ksteps);

    const int lrow = lane & 15;
    const int hi   = lane >> 4;
    const int rg0  = (wv & 1) * 16;        // wave's W-row group
    const int t0   = (wv >> 1) * 16;       // wave's token group
    const int r    = rg0 + lrow;           // this lane's W-row (for B-frag)
    const int sw   = r & 7;

    f32x4 accG = {0,0,0,0}, accU = {0,0,0,0};

    for (int m = 0; m < ksteps; ++m) {
        const int kbeg = (kbegstep + m) * BK;
        if (m) __syncthreads();            // prev step's LDS reads done
        // ---- stage: wave stages 16 of 64 row-chunks, 1 KB contiguous each
        #pragma unroll
        for (int c = 0; c < 16; ++c) {
            const int cid = wv * 16 + c;
            const int arr = cid >> 5;      // 0=G 1=U
            const int row = cid & 31;
            const float* base = (arr ? UW : GW) +
                (size_t)(i0 + row) * H_DIM + kbeg;
            gll16(base + ((lane ^ (row & 7)) << 2), &ldsw[arr][row][0]);
        }
        // ---- A-fragments (x) for this k-step: 8 slices
        bf16x8 xf[8];
        const __bf16* xp = XB + (size_t)(t0 + lrow) * H_DIM + kbeg + hi * 8;
        #pragma unroll
        for (int ks = 0; ks < 8; ++ks) xf[ks] = *(const bf16x8*)(xp + ks * 32);
        __syncthreads();                   // drains vmcnt -> LDS valid
        // ---- compute
        #pragma unroll
        for (int ks = 0; ks < 8; ++ks) {
            const int u0 = ks * 8 + hi * 2;       // logical 16B unit
            const char* gB = (const char*)&ldsw[0][r][0];
            const char* uB = (const char*)&ldsw[1][r][0];
            f32x4 gl = *(const f32x4*)(gB + ((u0 ^ sw) << 4));
            f32x4 gh = *(const f32x4*)(gB + (((u0 + 1) ^ sw) << 4));
            f32x4 ul = *(const f32x4*)(uB + ((u0 ^ sw) << 4));
            f32x4 uh = *(const f32x4*)(uB + (((u0 + 1) ^ sw) << 4));
            bf16x8 bg = cvt8(prune4(gl), prune4(gh));
            bf16x8 bu = cvt8(prune4(ul), prune4(uh));
            accG = __builtin_amdgcn_mfma_f32_16x16x32_bf16(xf[ks], bg, accG, 0, 0, 0);
            accU = __builtin_amdgcn_mfma_f32_16x16x32_bf16(xf[ks], bu, accU, 0, 0, 0);
        }
    }

    const int wcol = i0 + rg0 + lrow;      // W-row -> output col
    const int trow = t0 + hi * 4;          // token
    const size_t srow = (size_t)blockIdx.y * 32;
    #pragma unroll
    for (int q = 0; q < 4; ++q) {
        gpart[(srow + trow + q) * I_DIM + wcol] = accG[q];
        upart[(srow + trow + q) * I_DIM + wcol] = accU[q];
    }
}

__global__ __launch_bounds__(256) void k_hidden(
        const float* __restrict__ gpart, const float* __restrict__ upart,
        const float* __restrict__ gb, const float* __restrict__ ub,
        __bf16* __restrict__ hb, int nsplit) {
    const int i = blockIdx.x * 256 + threadIdx.x;  // 43*256 = 11008
    const int t = blockIdx.y;
    float g = gb[i], u = ub[i];
    for (int s = 0; s < nsplit; ++s) {
        g += gpart[(size_t)(s * 32 + t) * I_DIM + i];
        u += upart[(size_t)(s * 32 + t) * I_DIM + i];
    }
    float h = g / (1.0f + __expf(-g)) * u;   // silu(g)*u
    hb[(size_t)t * I_DIM + i] = (__bf16)h;
}

// down: same structure, one weight array, no prune. LDS 32 KiB.
__global__ __launch_bounds__(256) void k_down(
        const float* __restrict__ DW, const __bf16* __restrict__ HB,
        float* __restrict__ opart, int nsplit) {
    __shared__ float ldsd[32][BK];         // 32 KiB
    const int lane = threadIdx.x & 63;
    const int wv   = threadIdx.x >> 6;
    const int o0   = blockIdx.x * 32;      // 128 tiles
    int kbegstep, ksteps;
    ksplit(blockIdx.y, nsplit, KSTEPS_DN, kbegstep, ksteps);

    const int lrow = lane & 15;
    const int hi   = lane >> 4;
    const int rg0  = (wv & 1) * 16;
    const int t0   = (wv >> 1) * 16;
    const int r    = rg0 + lrow;
    const int sw   = r & 7;

    f32x4 acc = {0,0,0,0};

    for (int m = 0; m < ksteps; ++m) {
        const int kbeg = (kbegstep + m) * BK;
        if (m) __syncthreads();
        #pragma unroll
        for (int c = 0; c < 8; ++c) {
            const int row = wv * 8 + c;
            const float* base = DW + (size_t)(o0 + row) * I_DIM + kbeg;
            gll16(base + ((lane ^ (row & 7)) << 2), &ldsd[row][0]);
        }
        bf16x8 hf[8];
        const __bf16* hp = HB + (size_t)(t0 + lrow) * I_DIM + kbeg + hi * 8;
        #pragma unroll
        for (int ks = 0; ks < 8; ++ks) hf[ks] = *(const bf16x8*)(hp + ks * 32);
        __syncthreads();
        #pragma unroll
        for (int ks = 0; ks < 8; ++ks) {
            const int u0 = ks * 8 + hi * 2;
            const char* dB = (const char*)&ldsd[r][0];
            f32x4 dl = *(const f32x4*)(dB + ((u0 ^ sw) << 4));
            f32x4 dh = *(const f32x4*)(dB + (((u0 + 1) ^ sw) << 4));
            bf16x8 bw = cvt8(dl, dh);
            acc = __builtin_amdgcn_mfma_f32_16x16x32_bf16(hf[ks], bw, acc, 0, 0, 0);
        }
    }

    const int wcol = o0 + rg0 + lrow;
    const int trow = t0 + hi * 4;
    const size_t srow = (size_t)blockIdx.y * 32;
    #pragma unroll
    for (int q = 0; q < 4; ++q)
        opart[(srow + trow + q) * H_DIM + wcol] = acc[q];
}

__global__ __launch_bounds__(256) void k_out(
        const float* __restrict__ opart, const float* __restrict__ db,
        float* __restrict__ out, int nsplit) {
    const int o = blockIdx.x * 256 + threadIdx.x;  // 16*256 = 4096
    const int t = blockIdx.y;
    float v = db[o];
    for (int s = 0; s < nsplit; ++s)
        v += opart[(size_t)(s * 32 + t) * H_DIM + o];
    out[(size_t)t * H_DIM + o] = v;
}

extern "C" void kernel_launch(void* const* d_in, const int* in_sizes, int n_in,
                              void* d_out, int out_size, void* d_ws, size_t ws_size,
                              hipStream_t stream) {
    const float* x  = (const float*)d_in[0];
    const float* gw = (const float*)d_in[1];
    const float* uw = (const float*)d_in[2];
    const float* dw = (const float*)d_in[3];
    const float* gb = (const float*)d_in[4];
    const float* ub = (const float*)d_in[5];
    const float* db = (const float*)d_in[6];
    float* out = (float*)d_out;

    const size_t XB_BYTES = (size_t)32 * H_DIM * 2;          // 256 KiB
    const size_t HB_BYTES = (size_t)32 * I_DIM * 2;          // 688 KiB
    const size_t GP_UNIT  = (size_t)32 * I_DIM * 4;          // 1.38 MiB / split
    const size_t OP_UNIT  = (size_t)32 * H_DIM * 4;          // 0.5 MiB / split

    int ns1 = 4, ns2 = 4;
    while (ns1 > 2 &&
           XB_BYTES + HB_BYTES + 2 * GP_UNIT * ns1 + OP_UNIT * ns2 > ws_size)
        ns1 >>= 1;
    while (ns2 > 2 &&
           XB_BYTES + HB_BYTES + 2 * GP_UNIT * ns1 + OP_UNIT * ns2 > ws_size)
        ns2 >>= 1;

    char* ws = (char*)d_ws;
    __bf16* xb    = (__bf16*)(ws);
    __bf16* hb    = (__bf16*)(ws + XB_BYTES);
    float*  gpart = (float*)(ws + XB_BYTES + HB_BYTES);
    float*  upart = (float*)(ws + XB_BYTES + HB_BYTES + GP_UNIT * ns1);
    float*  opart = (float*)(ws + XB_BYTES + HB_BYTES + 2 * GP_UNIT * ns1);

    k_cvt_x <<<dim3(128),                dim3(256), 0, stream>>>(x, xb);
    k_gateup<<<dim3(I_DIM / 32, ns1),    dim3(256), 0, stream>>>(gw, uw, xb, gpart, upart, ns1);
    k_hidden<<<dim3(I_DIM / 256, 32),    dim3(256), 0, stream>>>(gpart, upart, gb, ub, hb, ns1);
    k_down  <<<dim3(H_DIM / 32, ns2),    dim3(256), 0, stream>>>(dw, hb, opart, ns2);
    k_out   <<<dim3(H_DIM / 256, 32),    dim3(256), 0, stream>>>(opart, db, out, ns2);
}

// Round 5
// 146.000 us; speedup vs baseline: 1.1546x; 1.1354x over previous
//
#include <hip/hip_runtime.h>

typedef float f32x4 __attribute__((ext_vector_type(4)));
typedef __bf16 bf16x8 __attribute__((ext_vector_type(8)));

#define H_DIM 4096
#define I_DIM 11008
#define BK 128                    // k floats per step = 512 B per row chunk
#define KSTEPS_GU (H_DIM / BK)    // 32
#define KSTEPS_DN (I_DIM / BK)    // 86

// 2:4 prune of one contiguous group of 4 (stable argsort tie semantics)
__device__ __forceinline__ f32x4 prune4(f32x4 w) {
    float a0 = fabsf(w[0]), a1 = fabsf(w[1]), a2 = fabsf(w[2]), a3 = fabsf(w[3]);
    int r0 = (int)(a1 < a0) + (int)(a2 < a0) + (int)(a3 < a0);
    int r1 = (int)(a0 <= a1) + (int)(a2 < a1) + (int)(a3 < a1);
    int r2 = (int)(a0 <= a2) + (int)(a1 <= a2) + (int)(a3 < a2);
    int r3 = (int)(a0 <= a3) + (int)(a1 <= a3) + (int)(a2 <= a3);
    w[0] = (r0 >= 2) ? w[0] : 0.0f;
    w[1] = (r1 >= 2) ? w[1] : 0.0f;
    w[2] = (r2 >= 2) ? w[2] : 0.0f;
    w[3] = (r3 >= 2) ? w[3] : 0.0f;
    return w;
}

__device__ __forceinline__ bf16x8 cvt8(f32x4 a, f32x4 b) {
    bf16x8 r;
    r[0] = (__bf16)a[0]; r[1] = (__bf16)a[1];
    r[2] = (__bf16)a[2]; r[3] = (__bf16)a[3];
    r[4] = (__bf16)b[0]; r[5] = (__bf16)b[1];
    r[6] = (__bf16)b[2]; r[7] = (__bf16)b[3];
    return r;
}

__device__ __forceinline__ void gll16(const void* g, void* l) {
    __builtin_amdgcn_global_load_lds(
        (const __attribute__((address_space(1))) void*)g,
        (__attribute__((address_space(3))) void*)l, 16, 0, 0);
}

__device__ __forceinline__ void ksplit(int s, int nsplit, int total,
                                       int& beg, int& cnt) {
    int q = total / nsplit, r = total % nsplit;
    cnt = q + (s < r ? 1 : 0);
    beg = s * q + (s < r ? s : r);
}

__global__ __launch_bounds__(256) void k_cvt_x(const float* __restrict__ x,
                                               __bf16* __restrict__ xb) {
    int i = (blockIdx.x * 256 + threadIdx.x) * 4;
    f32x4 v = *(const f32x4*)(x + i);
    xb[i + 0] = (__bf16)v[0]; xb[i + 1] = (__bf16)v[1];
    xb[i + 2] = (__bf16)v[2]; xb[i + 3] = (__bf16)v[3];
}

// gate+up fused, double-buffered LDS, m97-style schedule:
// [barrier] -> xf reg loads -> stage NEXT buffer -> compute current buffer.
// One gll16 stages 2 adjacent rows (512 B each, 1 KB linear LDS dest);
// source XOR-preswizzled (u ^ (row&7), 16B units) = read swizzle involution.
__global__ __launch_bounds__(256) void k_gateup(
        const float* __restrict__ GW, const float* __restrict__ UW,
        const __bf16* __restrict__ XB,
        float* __restrict__ gpart, float* __restrict__ upart, int nsplit) {
    __shared__ __align__(16) float ldsw[2][2][32][BK];   // [buf][G/U][row][k] 64 KiB
    const int lane = threadIdx.x & 63;
    const int wv   = threadIdx.x >> 6;
    const int i0   = blockIdx.x * 32;      // 344 tiles
    int kbegstep, ksteps;
    ksplit(blockIdx.y, nsplit, KSTEPS_GU, kbegstep, ksteps);

    const int lrow = lane & 15;
    const int hi   = lane >> 4;            // 0..3
    const int rg0  = (wv & 1) * 16;        // wave's W-row group
    const int t0   = (wv >> 1) * 16;       // wave's token group
    const int r    = rg0 + lrow;           // this lane's W-row (B-frag)
    const int sw   = r & 7;

    // staging assignment: 8 gll16 per wave, each = one (arr, row-pair)
    const int srow0 = (lane >> 5);         // 0/1: which row of the pair

    f32x4 accG = {0,0,0,0}, accU = {0,0,0,0};

    // ---- prologue: stage step 0 into buf 0
    {
        const int kbeg = kbegstep * BK;
        #pragma unroll
        for (int c = 0; c < 8; ++c) {
            const int cid  = wv * 8 + c;   // 0..31
            const int arr  = cid >> 4;     // 0=G, 1=U
            const int pr   = cid & 15;     // row pair
            const int row  = pr * 2 + srow0;
            const float* base = (arr ? UW : GW) + (size_t)(i0 + row) * H_DIM + kbeg;
            gll16(base + (((lane & 31) ^ (row & 7)) << 2), &ldsw[0][arr][pr * 2][0]);
        }
    }

    for (int m = 0; m < ksteps; ++m) {
        const int buf  = m & 1;
        const int kbeg = (kbegstep + m) * BK;
        __syncthreads();                   // buf[m&1] ready (vmcnt drained)

        // xf loads first (so their wait doesn't drain the stage queue)
        bf16x8 xf[4];
        const __bf16* xp = XB + (size_t)(t0 + lrow) * H_DIM + kbeg + hi * 8;
        #pragma unroll
        for (int ks = 0; ks < 4; ++ks) xf[ks] = *(const bf16x8*)(xp + ks * 32);

        // stage next step into the other buffer; flies during compute
        if (m + 1 < ksteps) {
            const int nkbeg = (kbegstep + m + 1) * BK;
            #pragma unroll
            for (int c = 0; c < 8; ++c) {
                const int cid  = wv * 8 + c;
                const int arr  = cid >> 4;
                const int pr   = cid & 15;
                const int row  = pr * 2 + srow0;
                const float* base = (arr ? UW : GW) + (size_t)(i0 + row) * H_DIM + nkbeg;
                gll16(base + (((lane & 31) ^ (row & 7)) << 2),
                      &ldsw[buf ^ 1][arr][pr * 2][0]);
            }
        }

        // compute on buf
        const char* gB = (const char*)&ldsw[buf][0][r][0];
        const char* uB = (const char*)&ldsw[buf][1][r][0];
        #pragma unroll
        for (int ks = 0; ks < 4; ++ks) {
            const int u0 = ks * 8 + hi * 2;           // 16B unit in row (0..31)
            f32x4 gl = *(const f32x4*)(gB + ((u0 ^ sw) << 4));
            f32x4 gh = *(const f32x4*)(gB + (((u0 + 1) ^ sw) << 4));
            f32x4 ul = *(const f32x4*)(uB + ((u0 ^ sw) << 4));
            f32x4 uh = *(const f32x4*)(uB + (((u0 + 1) ^ sw) << 4));
            bf16x8 bg = cvt8(prune4(gl), prune4(gh));
            bf16x8 bu = cvt8(prune4(ul), prune4(uh));
            accG = __builtin_amdgcn_mfma_f32_16x16x32_bf16(xf[ks], bg, accG, 0, 0, 0);
            accU = __builtin_amdgcn_mfma_f32_16x16x32_bf16(xf[ks], bu, accU, 0, 0, 0);
        }
    }

    const int wcol = i0 + rg0 + lrow;
    const int trow = t0 + hi * 4;
    const size_t srow = (size_t)blockIdx.y * 32;
    #pragma unroll
    for (int q = 0; q < 4; ++q) {
        gpart[(srow + trow + q) * I_DIM + wcol] = accG[q];
        upart[(srow + trow + q) * I_DIM + wcol] = accU[q];
    }
}

__global__ __launch_bounds__(256) void k_hidden(
        const float* __restrict__ gpart, const float* __restrict__ upart,
        const float* __restrict__ gb, const float* __restrict__ ub,
        __bf16* __restrict__ hb, int nsplit) {
    const int i = blockIdx.x * 256 + threadIdx.x;  // 43*256 = 11008
    const int t = blockIdx.y;
    float g = gb[i], u = ub[i];
    for (int s = 0; s < nsplit; ++s) {
        g += gpart[(size_t)(s * 32 + t) * I_DIM + i];
        u += upart[(size_t)(s * 32 + t) * I_DIM + i];
    }
    float h = g / (1.0f + __expf(-g)) * u;   // silu(g)*u
    hb[(size_t)t * I_DIM + i] = (__bf16)h;
}

// down: same dbuf schedule, one array, no prune. LDS 32 KiB.
__global__ __launch_bounds__(256) void k_down(
        const float* __restrict__ DW, const __bf16* __restrict__ HB,
        float* __restrict__ opart, int nsplit) {
    __shared__ __align__(16) float ldsd[2][32][BK];      // 32 KiB
    const int lane = threadIdx.x & 63;
    const int wv   = threadIdx.x >> 6;
    const int o0   = blockIdx.x * 32;      // 128 tiles
    int kbegstep, ksteps;
    ksplit(blockIdx.y, nsplit, KSTEPS_DN, kbegstep, ksteps);

    const int lrow = lane & 15;
    const int hi   = lane >> 4;
    const int rg0  = (wv & 1) * 16;
    const int t0   = (wv >> 1) * 16;
    const int r    = rg0 + lrow;
    const int sw   = r & 7;
    const int srow0 = (lane >> 5);

    f32x4 acc = {0,0,0,0};

    {
        const int kbeg = kbegstep * BK;
        #pragma unroll
        for (int c = 0; c < 4; ++c) {
            const int pr  = wv * 4 + c;    // 0..15
            const int row = pr * 2 + srow0;
            const float* base = DW + (size_t)(o0 + row) * I_DIM + kbeg;
            gll16(base + (((lane & 31) ^ (row & 7)) << 2), &ldsd[0][pr * 2][0]);
        }
    }

    for (int m = 0; m < ksteps; ++m) {
        const int buf  = m & 1;
        const int kbeg = (kbegstep + m) * BK;
        __syncthreads();

        bf16x8 hf[4];
        const __bf16* hp = HB + (size_t)(t0 + lrow) * I_DIM + kbeg + hi * 8;
        #pragma unroll
        for (int ks = 0; ks < 4; ++ks) hf[ks] = *(const bf16x8*)(hp + ks * 32);

        if (m + 1 < ksteps) {
            const int nkbeg = (kbegstep + m + 1) * BK;
            #pragma unroll
            for (int c = 0; c < 4; ++c) {
                const int pr  = wv * 4 + c;
                const int row = pr * 2 + srow0;
                const float* base = DW + (size_t)(o0 + row) * I_DIM + nkbeg;
                gll16(base + (((lane & 31) ^ (row & 7)) << 2),
                      &ldsd[buf ^ 1][pr * 2][0]);
            }
        }

        const char* dB = (const char*)&ldsd[buf][r][0];
        #pragma unroll
        for (int ks = 0; ks < 4; ++ks) {
            const int u0 = ks * 8 + hi * 2;
            f32x4 dl = *(const f32x4*)(dB + ((u0 ^ sw) << 4));
            f32x4 dh = *(const f32x4*)(dB + (((u0 + 1) ^ sw) << 4));
            bf16x8 bw = cvt8(dl, dh);
            acc = __builtin_amdgcn_mfma_f32_16x16x32_bf16(hf[ks], bw, acc, 0, 0, 0);
        }
    }

    const int wcol = o0 + rg0 + lrow;
    const int trow = t0 + hi * 4;
    const size_t srow = (size_t)blockIdx.y * 32;
    #pragma unroll
    for (int q = 0; q < 4; ++q)
        opart[(srow + trow + q) * H_DIM + wcol] = acc[q];
}

__global__ __launch_bounds__(256) void k_out(
        const float* __restrict__ opart, const float* __restrict__ db,
        float* __restrict__ out, int nsplit) {
    const int o = blockIdx.x * 256 + threadIdx.x;  // 16*256 = 4096
    const int t = blockIdx.y;
    float v = db[o];
    for (int s = 0; s < nsplit; ++s)
        v += opart[(size_t)(s * 32 + t) * H_DIM + o];
    out[(size_t)t * H_DIM + o] = v;
}

extern "C" void kernel_launch(void* const* d_in, const int* in_sizes, int n_in,
                              void* d_out, int out_size, void* d_ws, size_t ws_size,
                              hipStream_t stream) {
    const float* x  = (const float*)d_in[0];
    const float* gw = (const float*)d_in[1];
    const float* uw = (const float*)d_in[2];
    const float* dw = (const float*)d_in[3];
    const float* gb = (const float*)d_in[4];
    const float* ub = (const float*)d_in[5];
    const float* db = (const float*)d_in[6];
    float* out = (float*)d_out;

    const size_t XB_BYTES = (size_t)32 * H_DIM * 2;          // 256 KiB
    const size_t HB_BYTES = (size_t)32 * I_DIM * 2;          // 688 KiB
    const size_t GP_UNIT  = (size_t)32 * I_DIM * 4;          // 1.38 MiB / split
    const size_t OP_UNIT  = (size_t)32 * H_DIM * 4;          // 0.5 MiB / split

    int ns1 = 4, ns2 = 8;
    while (ns1 > 2 &&
           XB_BYTES + HB_BYTES + 2 * GP_UNIT * ns1 + OP_UNIT * ns2 > ws_size)
        ns1 >>= 1;
    while (ns2 > 2 &&
           XB_BYTES + HB_BYTES + 2 * GP_UNIT * ns1 + OP_UNIT * ns2 > ws_size)
        ns2 >>= 1;

    char* ws = (char*)d_ws;
    __bf16* xb    = (__bf16*)(ws);
    __bf16* hb    = (__bf16*)(ws + XB_BYTES);
    float*  gpart = (float*)(ws + XB_BYTES + HB_BYTES);
    float*  upart = (float*)(ws + XB_BYTES + HB_BYTES + GP_UNIT * ns1);
    float*  opart = (float*)(ws + XB_BYTES + HB_BYTES + 2 * GP_UNIT * ns1);

    k_cvt_x <<<dim3(128),                dim3(256), 0, stream>>>(x, xb);
    k_gateup<<<dim3(I_DIM / 32, ns1),    dim3(256), 0, stream>>>(gw, uw, xb, gpart, upart, ns1);
    k_hidden<<<dim3(I_DIM / 256, 32),    dim3(256), 0, stream>>>(gpart, upart, gb, ub, hb, ns1);
    k_down  <<<dim3(H_DIM / 32, ns2),    dim3(256), 0, stream>>>(dw, hb, opart, ns2);
    k_out   <<<dim3(H_DIM / 256, 32),    dim3(256), 0, stream>>>(opart, db, out, ns2);
}